// Round 8
// baseline (841.457 us; speedup 1.0000x reference)
//
#include <hip/hip_runtime.h>
#include <math.h>

#define NN 20000   // nodes
#define NE 320000  // edges (without self-loops)
#define TT 8       // timesteps
#define D1 256     // H*F layer-1 width
#define CD 32      // layer-2 width == LSTM hidden
#define PG1 1024   // persistent grid, k_fused8 (4 blocks/CU)
#define PG2 2048   // persistent grid, k_agg2_8

// ---------------- CSR build (once per launch; edges identical across t) ----------------

__global__ __launch_bounds__(256) void k_deg(const int* __restrict__ dst, int* __restrict__ deg) {
  int e = blockIdx.x * 256 + threadIdx.x;
  if (e < NE) atomicAdd(&deg[dst[e]], 1);
}

__global__ __launch_bounds__(1024) void k_scan(const int* __restrict__ deg,
                                               int* __restrict__ rowptr, int* __restrict__ fill) {
  __shared__ int sd[1024];
  __shared__ int carry_s;
  int tid = threadIdx.x;
  if (tid == 0) { carry_s = 0; rowptr[0] = 0; }
  __syncthreads();
  for (int base = 0; base < NN; base += 1024) {
    int i = base + tid;
    int v = (i < NN) ? deg[i] : 0;
    sd[tid] = v;
    __syncthreads();
    for (int off = 1; off < 1024; off <<= 1) {
      int t = (tid >= off) ? sd[tid - off] : 0;
      __syncthreads();
      sd[tid] += t;
      __syncthreads();
    }
    int incl = sd[tid];
    int carry = carry_s;
    if (i < NN) { rowptr[i + 1] = carry + incl; fill[i] = carry + incl - v; }
    __syncthreads();
    if (tid == 1023) carry_s = carry + sd[1023];
    __syncthreads();
  }
}

__global__ __launch_bounds__(256) void k_fill(const int* __restrict__ src, const int* __restrict__ dst,
                                              int* __restrict__ fill, int* __restrict__ csr) {
  int e = blockIdx.x * 256 + threadIdx.x;
  if (e < NE) {
    int pos = atomicAdd(&fill[dst[e]], 1);
    csr[pos] = src[e];
  }
}

// ---------------- one-time: folded attention vectors + weight transposes --------------------

__global__ __launch_bounds__(256) void k_prew(const float* __restrict__ W1,
    const float* __restrict__ as1, const float* __restrict__ ad1,
    const float* __restrict__ W2,
    float* __restrict__ wsrc, float* __restrict__ wdst,
    float* __restrict__ W1T, float* __restrict__ W2T) {
  int tid = threadIdx.x;
  int k = tid >> 3, h = tid & 7;
  float s = 0.f, d = 0.f;
  #pragma unroll
  for (int f = 0; f < 32; ++f) {
    float wv = W1[k * D1 + h * 32 + f];
    s = fmaf(wv, as1[h * 32 + f], s);
    d = fmaf(wv, ad1[h * 32 + f], d);
  }
  wsrc[k * 8 + h] = s;
  wdst[k * 8 + h] = d;
  for (int i = tid; i < D1 * 32; i += 256) {
    int j = i >> 5, kk = i & 31;
    W1T[i] = W1[kk * D1 + j];          // W1T[j*32+kk]
  }
  for (int i = tid; i < 32 * D1; i += 256) {
    int f = i >> 8, kk = i & 255;
    W2T[i] = W2[kk * CD + f];          // W2T[f*256+kk]
  }
}

// ---------------- logits for all t: als/ald = x @ w~ ; t = blockIdx.x & 7 -------------------

__global__ __launch_bounds__(256) void k_logits8(const float* __restrict__ x,
    const float* __restrict__ wsrc, const float* __restrict__ wdst,
    float* __restrict__ als, float* __restrict__ ald) {
  __shared__ float xs[32 * 33];
  __shared__ float wsr[256], wdr[256];
  int tid = threadIdx.x;
  int t = blockIdx.x & 7;
  int n0 = (blockIdx.x >> 3) * 32;
  const float* xt = x + (size_t)t * NN * 32;
  int nl = tid >> 3, h = tid & 7;
  for (int i = tid; i < 1024; i += 256) {
    int g = i >> 5, k = i & 31;
    xs[g * 33 + k] = xt[n0 * 32 + i];
  }
  wsr[tid] = wsrc[tid];
  wdr[tid] = wdst[tid];
  __syncthreads();
  const float* xr = xs + nl * 33;
  float as = 0.f, ad = 0.f;
  #pragma unroll
  for (int k = 0; k < 32; ++k) {
    float xv = xr[k];
    as = fmaf(xv, wsr[k * 8 + h], as);
    ad = fmaf(xv, wdr[k * 8 + h], ad);
  }
  als[(size_t)t * NN * 8 + n0 * 8 + tid] = as;
  ald[(size_t)t * NN * 8 + n0 * 8 + tid] = ad;
}

// ---------------- fused layer-1 gather + post1 GEMM + layer-2 GEMM -------------------------
// Phase 1 is two-pass per wave: pass A computes exp-weights edge-parallel (one exp per
// (edge,head), coalesced als reads) into a wave-private LDS slice; after a wave-local
// s_waitcnt lgkmcnt(0) (no barrier), pass B reads ids+weights back as b128 broadcasts and
// issues 8 gathers back-to-back. Pads carry ew=0 (exact no-op).

__global__ __launch_bounds__(256, 4) void k_fused8(const float* __restrict__ x,
    const float* __restrict__ W1T, const float* __restrict__ b1,
    const float* __restrict__ W2T, const float* __restrict__ as2, const float* __restrict__ ad2,
    const float* __restrict__ als, const float* __restrict__ ald,
    const int* __restrict__ rowptr, const int* __restrict__ csr,
    float* __restrict__ h2, float* __restrict__ al2s, float* __restrict__ al2d) {
  __shared__ float aggp[4][256];   // per-wave partial gather
  __shared__ float denp[4][8];
  __shared__ float aggs[2][256];   // combined per node
  __shared__ float dens[2][8];
  __shared__ float rels[2][256];
  __shared__ float part[4][2][32];
  __shared__ float ewsA[4][64];    // wave-private exp weights [h*8+e]
  __shared__ int   siA[4][8];      // wave-private src ids
  int tid = threadIdx.x;

  // weight columns (L1-resident reloads are absorbed; see R7 post-mortem)
  int j = tid;
  float4 w1v[8];
  const float4* w1p = (const float4*)(W1T + j * 32);
  #pragma unroll
  for (int q8 = 0; q8 < 8; ++q8) w1v[q8] = w1p[q8];
  float bj = b1[j];
  int q = tid >> 5, f = tid & 31;
  float4 w2v[8];
  const float4* w2p = (const float4*)(W2T + f * 256 + q * 32);
  #pragma unroll
  for (int q8 = 0; q8 < 8; ++q8) w2v[q8] = w2p[q8];
  float as2f = as2[f], ad2f = ad2[f];

  int wv = tid >> 6, lane = tid & 63;
  int h = lane >> 3, fb = lane & 7;      // pass-B mapping
  int eA = lane >> 3, hA = lane & 7;     // pass-A mapping (coalesced als)
  int l_wave = wv >> 1, half = wv & 1;

  const int NG = (NN / 2) * TT;    // 80000 (t, node-pair) groups
  for (int it = 0; it < (NG + PG1 - 1) / PG1; ++it) {
    int g = blockIdx.x + it * PG1;
    bool active = g < NG;
    int t = g & 7;
    int n0 = (g >> 3) * 2;
    const float* xt = x + (size_t)t * NN * 32;
    const float* alst = als + (size_t)t * NN * 8;
    const float* aldt = ald + (size_t)t * NN * 8;

    // ---- phase 1: two-pass gather; wave (l_wave, half) takes half the edge list
    if (active) {
      int n = n0 + l_wave;
      const float4* x4 = (const float4*)xt;
      float4 acc = make_float4(0.f, 0.f, 0.f, 0.f);
      float den = 0.f;
      int beg = rowptr[n], end = rowptr[n + 1];
      int mid = beg + ((end - beg + 1) >> 1);
      int lo = half ? mid : beg;
      int hi = half ? end : mid;
      float adA = aldt[n * 8 + hA];
      for (int b = lo; b < hi; b += 8) {
        // pass A: lane (eA, hA) computes ew for edge-slot eA, head hA
        int idx = b + eA;
        float ew = 0.f; int s = n;
        if (idx < hi) {
          s = csr[idx];
          float a = alst[s * 8 + hA] + adA;
          a = a > 0.f ? a : 0.2f * a;
          ew = __expf(a);
        }
        ewsA[wv][hA * 8 + eA] = ew;
        if (hA == 0) siA[wv][eA] = s;
        asm volatile("s_waitcnt lgkmcnt(0)" ::: "memory");  // wave-local: writes visible
        // pass B: broadcast-read ids+weights, 8 gathers in flight
        int4 sa = *(const int4*)&siA[wv][0];
        int4 sb = *(const int4*)&siA[wv][4];
        float4 ea = *(const float4*)&ewsA[wv][h * 8];
        float4 eb = *(const float4*)&ewsA[wv][h * 8 + 4];
        float4 v0 = x4[(size_t)sa.x * 8 + fb];
        float4 v1 = x4[(size_t)sa.y * 8 + fb];
        float4 v2 = x4[(size_t)sa.z * 8 + fb];
        float4 v3 = x4[(size_t)sa.w * 8 + fb];
        float4 v4 = x4[(size_t)sb.x * 8 + fb];
        float4 v5 = x4[(size_t)sb.y * 8 + fb];
        float4 v6 = x4[(size_t)sb.z * 8 + fb];
        float4 v7 = x4[(size_t)sb.w * 8 + fb];
        acc.x = fmaf(ea.x, v0.x, acc.x); acc.y = fmaf(ea.x, v0.y, acc.y);
        acc.z = fmaf(ea.x, v0.z, acc.z); acc.w = fmaf(ea.x, v0.w, acc.w); den += ea.x;
        acc.x = fmaf(ea.y, v1.x, acc.x); acc.y = fmaf(ea.y, v1.y, acc.y);
        acc.z = fmaf(ea.y, v1.z, acc.z); acc.w = fmaf(ea.y, v1.w, acc.w); den += ea.y;
        acc.x = fmaf(ea.z, v2.x, acc.x); acc.y = fmaf(ea.z, v2.y, acc.y);
        acc.z = fmaf(ea.z, v2.z, acc.z); acc.w = fmaf(ea.z, v2.w, acc.w); den += ea.z;
        acc.x = fmaf(ea.w, v3.x, acc.x); acc.y = fmaf(ea.w, v3.y, acc.y);
        acc.z = fmaf(ea.w, v3.z, acc.z); acc.w = fmaf(ea.w, v3.w, acc.w); den += ea.w;
        acc.x = fmaf(eb.x, v4.x, acc.x); acc.y = fmaf(eb.x, v4.y, acc.y);
        acc.z = fmaf(eb.x, v4.z, acc.z); acc.w = fmaf(eb.x, v4.w, acc.w); den += eb.x;
        acc.x = fmaf(eb.y, v5.x, acc.x); acc.y = fmaf(eb.y, v5.y, acc.y);
        acc.z = fmaf(eb.y, v5.z, acc.z); acc.w = fmaf(eb.y, v5.w, acc.w); den += eb.y;
        acc.x = fmaf(eb.z, v6.x, acc.x); acc.y = fmaf(eb.z, v6.y, acc.y);
        acc.z = fmaf(eb.z, v6.z, acc.z); acc.w = fmaf(eb.z, v6.w, acc.w); den += eb.z;
        acc.x = fmaf(eb.w, v7.x, acc.x); acc.y = fmaf(eb.w, v7.y, acc.y);
        acc.z = fmaf(eb.w, v7.z, acc.z); acc.w = fmaf(eb.w, v7.w, acc.w); den += eb.w;
      }
      if (half) {  // self-loop
        float a = alst[n * 8 + h] + aldt[n * 8 + h];
        a = a > 0.f ? a : 0.2f * a;
        float e = __expf(a);
        float4 v = x4[(size_t)n * 8 + fb];
        acc.x = fmaf(e, v.x, acc.x);
        acc.y = fmaf(e, v.y, acc.y);
        acc.z = fmaf(e, v.z, acc.z);
        acc.w = fmaf(e, v.w, acc.w);
        den += e;
      }
      *(float4*)(&aggp[wv][h * 32 + fb * 4]) = acc;
      if (fb == 0) denp[wv][h] = den;
    }
    __syncthreads();

    // ---- combine halves
    if (active) {
      #pragma unroll
      for (int l = 0; l < 2; ++l) aggs[l][j] = aggp[2 * l][j] + aggp[2 * l + 1][j];
      if (tid < 16) {
        int l = tid >> 3, hh = tid & 7;
        dens[l][hh] = denp[2 * l][hh] + denp[2 * l + 1][hh];
      }
    }
    __syncthreads();

    // ---- phase 2: rel1 = relu(agg @ W1_head / den + b1)
    if (active) {
      int hj = j >> 5;
      #pragma unroll
      for (int l = 0; l < 2; ++l) {
        const float4* ar4 = (const float4*)(&aggs[l][hj * 32]);
        float a = 0.f;
        #pragma unroll
        for (int k4 = 0; k4 < 8; ++k4) {
          float4 av = ar4[k4];
          a = fmaf(av.x, w1v[k4].x, fmaf(av.y, w1v[k4].y,
              fmaf(av.z, w1v[k4].z, fmaf(av.w, w1v[k4].w, a))));
        }
        float v = fmaf(a, 1.f / dens[l][hj], bj);
        rels[l][j] = fmaxf(v, 0.f);
      }
    }
    __syncthreads();

    // ---- phase 3: h2 = rel1 @ W2 (k-split over q, reduce via shuffle + LDS)
    if (active) {
      float accg[2];
      #pragma unroll
      for (int l = 0; l < 2; ++l) {
        const float4* r4 = (const float4*)(&rels[l][q * 32]);
        float a = 0.f;
        #pragma unroll
        for (int jj = 0; jj < 8; ++jj) {
          float4 a4 = r4[jj];
          a = fmaf(a4.x, w2v[jj].x, fmaf(a4.y, w2v[jj].y,
              fmaf(a4.z, w2v[jj].z, fmaf(a4.w, w2v[jj].w, a))));
        }
        a += __shfl_xor(a, 32, 64);
        accg[l] = a;
      }
      if ((tid & 32) == 0) {
        #pragma unroll
        for (int l = 0; l < 2; ++l) part[wv][l][f] = accg[l];
      }
    }
    __syncthreads();

    if (active && tid < 64) {
      int l = tid >> 5, ff = tid & 31;
      float v = part[0][l][ff] + part[1][l][ff] + part[2][l][ff] + part[3][l][ff];
      int nn = n0 + l;
      h2[((size_t)t * NN + nn) * CD + ff] = v;
      float vs = v * as2f, vd = v * ad2f;
      #pragma unroll
      for (int m = 1; m < 32; m <<= 1) {
        vs += __shfl_xor(vs, m, 64);
        vd += __shfl_xor(vd, m, 64);
      }
      if (ff == 0) {
        al2s[(size_t)t * NN + nn] = vs;
        al2d[(size_t)t * NN + nn] = vd;
      }
    }
    __syncthreads();
  }
}

// ---------------- GAT layer 2 aggregation: persistent, wave = 2 nodes, two-pass -------------
// Pass A: lane (node=lane>>5, slot=lane&31) computes ew edge-parallel into wave-private LDS.
// Pass B: b128 broadcast reads of ids+weights, 32 gathers in flight per half-wave.

__global__ __launch_bounds__(256, 4) void k_agg2_8(const float* __restrict__ h2,
    const float* __restrict__ al2s, const float* __restrict__ al2d,
    const int* __restrict__ rowptr, const int* __restrict__ csr,
    const float* __restrict__ b2, float* __restrict__ out) {
  __shared__ float ews2[4][64];
  __shared__ int   si2[4][64];
  int tid = threadIdx.x;
  int wv = tid >> 6, lane = tid & 63;
  int nd = lane >> 5, f = lane & 31;   // same node split in both passes
  float b2f = b2[f];
  const int NG = (NN / 2) * TT;        // 80000 wave-groups of 2 nodes
  for (int g = blockIdx.x * 4 + wv; g < NG; g += PG2 * 4) {
    int t = g & 7;
    int n = (g >> 3) * 2 + nd;
    const float* h2t = h2 + (size_t)t * NN * CD;
    const float* alst = al2s + (size_t)t * NN;
    const float* aldt = al2d + (size_t)t * NN;
    float ad = aldt[n];
    int beg = rowptr[n], end = rowptr[n + 1];
    int deg = end - beg;
    int dego = __shfl_xor(deg, 32, 64);
    int nb = ((deg > dego ? deg : dego) + 31) >> 5;
    float acc = 0.f, den = 0.f;
    for (int c = 0; c < nb; ++c) {
      int idx = beg + c * 32 + f;
      float ew = 0.f; int s = n;
      if (idx < end) {
        s = csr[idx];
        float a = alst[s] + ad;
        a = a > 0.f ? a : 0.2f * a;
        ew = __expf(a);
      }
      ews2[wv][lane] = ew;
      si2[wv][lane] = s;
      asm volatile("s_waitcnt lgkmcnt(0)" ::: "memory");  // wave-local
      #pragma unroll
      for (int u4 = 0; u4 < 8; ++u4) {
        int4 s4 = *(const int4*)&si2[wv][nd * 32 + u4 * 4];
        float4 e4 = *(const float4*)&ews2[wv][nd * 32 + u4 * 4];
        float v0 = h2t[(size_t)s4.x * CD + f];
        float v1 = h2t[(size_t)s4.y * CD + f];
        float v2 = h2t[(size_t)s4.z * CD + f];
        float v3 = h2t[(size_t)s4.w * CD + f];
        acc = fmaf(e4.x, v0, acc); den += e4.x;
        acc = fmaf(e4.y, v1, acc); den += e4.y;
        acc = fmaf(e4.z, v2, acc); den += e4.z;
        acc = fmaf(e4.w, v3, acc); den += e4.w;
      }
    }
    {  // self-loop
      float a = alst[n] + ad;
      a = a > 0.f ? a : 0.2f * a;
      float e = __expf(a);
      acc = fmaf(e, h2t[(size_t)n * CD + f], acc);
      den += e;
    }
    out[((size_t)t * NN + n) * CD + f] = acc / den + b2f;
  }
}

// ---------------- LSTM, all t in one kernel: weights in VGPRs, h/c in LDS ------------------

__global__ __launch_bounds__(256) void k_lstm_all(const float* __restrict__ agg2o,
    const float* __restrict__ w_ih, const float* __restrict__ w_hh,
    const float* __restrict__ b_ih, const float* __restrict__ b_hh,
    float* __restrict__ out) {
  __shared__ float xs[16 * 32], hs[16 * 32], cs[16 * 32], pre[16 * 128];
  int tid = threadIdx.x;
  int slot = tid >> 7;
  int r = tid & 127;
  float4 wi[8], wh[8];
  const float4* wi4 = (const float4*)(w_ih + r * 32);
  const float4* wh4 = (const float4*)(w_hh + r * 32);
  #pragma unroll
  for (int q = 0; q < 8; ++q) { wi[q] = wi4[q]; wh[q] = wh4[q]; }
  float bias = b_ih[r] + b_hh[r];
  int base = blockIdx.x * 16;
  for (int i = tid; i < 512; i += 256) { hs[i] = 0.f; cs[i] = 0.f; }
  for (int t = 0; t < TT; ++t) {
    for (int i = tid; i < 512; i += 256) xs[i] = agg2o[(size_t)t * NN * 32 + base * 32 + i];
    __syncthreads();
    #pragma unroll
    for (int g = 0; g < 8; ++g) {
      int nl = slot * 8 + g;
      const float4* xv4 = (const float4*)(xs + nl * 32);
      const float4* hv4 = (const float4*)(hs + nl * 32);
      float acc = bias;
      #pragma unroll
      for (int q = 0; q < 8; ++q) {
        float4 a = xv4[q], b = hv4[q];
        acc = fmaf(a.x, wi[q].x, acc);
        acc = fmaf(a.y, wi[q].y, acc);
        acc = fmaf(a.z, wi[q].z, acc);
        acc = fmaf(a.w, wi[q].w, acc);
        acc = fmaf(b.x, wh[q].x, acc);
        acc = fmaf(b.y, wh[q].y, acc);
        acc = fmaf(b.z, wh[q].z, acc);
        acc = fmaf(b.w, wh[q].w, acc);
      }
      pre[nl * 128 + r] = acc;
    }
    __syncthreads();
    for (int i = tid; i < 512; i += 256) {
      int nl = i >> 5, k = i & 31;
      float ai = pre[nl * 128 + k];
      float af = pre[nl * 128 + 32 + k];
      float ag = pre[nl * 128 + 64 + k];
      float ao = pre[nl * 128 + 96 + k];
      float ii = 1.f / (1.f + __expf(-ai));
      float ff = 1.f / (1.f + __expf(-af));
      float gg = tanhf(ag);
      float oo = 1.f / (1.f + __expf(-ao));
      float cn = fmaf(ff, cs[i], ii * gg);
      float hn = oo * tanhf(cn);
      cs[i] = cn; hs[i] = hn;
      out[(size_t)t * NN * 32 + base * 32 + i] = hn;
    }
  }
}

// ---------------- softmax over nodes, coalesced two-pass ----------------

__global__ __launch_bounds__(256) void k_sm_sum(const float* __restrict__ out, float* __restrict__ sums) {
  int t = blockIdx.y;
  const float4* b4 = (const float4*)(out + ((size_t)t * NN + blockIdx.x * 800) * CD);
  int tid = threadIdx.x;
  float4 s4 = make_float4(0.f, 0.f, 0.f, 0.f);
  for (int i = tid; i < 6400; i += 256) {
    float4 v = b4[i];
    s4.x += __expf(v.x); s4.y += __expf(v.y);
    s4.z += __expf(v.z); s4.w += __expf(v.w);
  }
  __shared__ float4 red[256];
  red[tid] = s4;
  __syncthreads();
  for (int off = 128; off >= 8; off >>= 1) {
    if (tid < off) {
      float4 o = red[tid + off];
      red[tid].x += o.x; red[tid].y += o.y; red[tid].z += o.z; red[tid].w += o.w;
    }
    __syncthreads();
  }
  if (tid < 8) {
    float4 v = red[tid];
    int c0 = tid * 4;
    atomicAdd(&sums[t * CD + c0 + 0], v.x);
    atomicAdd(&sums[t * CD + c0 + 1], v.y);
    atomicAdd(&sums[t * CD + c0 + 2], v.z);
    atomicAdd(&sums[t * CD + c0 + 3], v.w);
  }
}

__global__ __launch_bounds__(256) void k_sm_scale(float* __restrict__ out, const float* __restrict__ sums) {
  int t = blockIdx.y;
  __shared__ float inv[CD];
  int tid = threadIdx.x;
  if (tid < CD) inv[tid] = 1.f / sums[t * CD + tid];
  __syncthreads();
  float4* b4 = (float4*)(out + ((size_t)t * NN + blockIdx.x * 800) * CD);
  for (int i = tid; i < 6400; i += 256) {
    float4 v = b4[i];
    int c0 = (4 * i) & 31;
    v.x = __expf(v.x) * inv[c0];
    v.y = __expf(v.y) * inv[c0 + 1];
    v.z = __expf(v.z) * inv[c0 + 2];
    v.w = __expf(v.w) * inv[c0 + 3];
    b4[i] = v;
  }
}

// ---------------- launch ----------------

extern "C" void kernel_launch(void* const* d_in, const int* in_sizes, int n_in,
                              void* d_out, int out_size, void* d_ws, size_t ws_size,
                              hipStream_t stream) {
  const float* x   = (const float*)d_in[0];
  const float* W1  = (const float*)d_in[1];
  const float* as1 = (const float*)d_in[2];
  const float* ad1 = (const float*)d_in[3];
  const float* b1  = (const float*)d_in[4];
  const float* W2  = (const float*)d_in[5];
  const float* as2 = (const float*)d_in[6];
  const float* ad2 = (const float*)d_in[7];
  const float* b2  = (const float*)d_in[8];
  const float* wih = (const float*)d_in[9];
  const float* whh = (const float*)d_in[10];
  const float* bih = (const float*)d_in[11];
  const float* bhh = (const float*)d_in[12];
  const int*   ei  = (const int*)d_in[13];
  const int* srcp = ei;
  const int* dstp = ei + NE;
  float* out = (float*)d_out;

  float* ws = (float*)d_ws;
  float* al1s  = ws;  ws += (size_t)TT * NN * 8;
  float* al1d  = ws;  ws += (size_t)TT * NN * 8;
  float* h2    = ws;  ws += (size_t)TT * NN * CD;
  float* al2s  = ws;  ws += (size_t)TT * NN;
  float* al2d  = ws;  ws += (size_t)TT * NN;
  float* agg2o = ws;  ws += (size_t)TT * NN * CD;
  float* sums  = ws;  ws += TT * CD;
  float* wsrc  = ws;  ws += 256;
  float* wdst  = ws;  ws += 256;
  float* W1T   = ws;  ws += D1 * 32;
  float* W2T   = ws;  ws += 32 * D1;
  int* rowptr = (int*)ws;
  int* fill   = rowptr + NN + 1;
  int* csr    = fill + NN;
  int* deg    = csr + NE;

  hipMemsetAsync(sums, 0, TT * CD * sizeof(float), stream);
  hipMemsetAsync(deg, 0, NN * sizeof(int), stream);

  k_deg<<<(NE + 255) / 256, 256, 0, stream>>>(dstp, deg);
  k_scan<<<1, 1024, 0, stream>>>(deg, rowptr, fill);
  k_fill<<<(NE + 255) / 256, 256, 0, stream>>>(srcp, dstp, fill, csr);
  k_prew<<<1, 256, 0, stream>>>(W1, as1, ad1, W2, wsrc, wdst, W1T, W2T);

  k_logits8<<<(NN / 32) * TT, 256, 0, stream>>>(x, wsrc, wdst, al1s, al1d);
  k_fused8<<<PG1, 256, 0, stream>>>(x, W1T, b1, W2T, as2, ad2,
                                    al1s, al1d, rowptr, csr, h2, al2s, al2d);
  k_agg2_8<<<PG2, 256, 0, stream>>>(h2, al2s, al2d, rowptr, csr, b2, agg2o);
  k_lstm_all<<<NN / 16, 256, 0, stream>>>(agg2o, wih, whh, bih, bhh, out);

  k_sm_sum<<<dim3(25, TT), 256, 0, stream>>>(out, sums);
  k_sm_scale<<<dim3(25, TT), 256, 0, stream>>>(out, sums);
}

// Round 9
// 639.324 us; speedup vs baseline: 1.3162x; 1.3162x over previous
//
#include <hip/hip_runtime.h>
#include <math.h>

#define NN 20000   // nodes
#define NE 320000  // edges (without self-loops)
#define TT 8       // timesteps
#define D1 256     // H*F layer-1 width
#define CD 32      // layer-2 width == LSTM hidden

// ---------------- CSR build (once per launch; edges identical across t) ----------------

__global__ __launch_bounds__(256) void k_deg(const int* __restrict__ dst, int* __restrict__ deg) {
  int e = blockIdx.x * 256 + threadIdx.x;
  if (e < NE) atomicAdd(&deg[dst[e]], 1);
}

__global__ __launch_bounds__(1024) void k_scan(const int* __restrict__ deg,
                                               int* __restrict__ rowptr, int* __restrict__ fill) {
  __shared__ int sd[1024];
  __shared__ int carry_s;
  int tid = threadIdx.x;
  if (tid == 0) { carry_s = 0; rowptr[0] = 0; }
  __syncthreads();
  for (int base = 0; base < NN; base += 1024) {
    int i = base + tid;
    int v = (i < NN) ? deg[i] : 0;
    sd[tid] = v;
    __syncthreads();
    for (int off = 1; off < 1024; off <<= 1) {
      int t = (tid >= off) ? sd[tid - off] : 0;
      __syncthreads();
      sd[tid] += t;
      __syncthreads();
    }
    int incl = sd[tid];
    int carry = carry_s;
    if (i < NN) { rowptr[i + 1] = carry + incl; fill[i] = carry + incl - v; }
    __syncthreads();
    if (tid == 1023) carry_s = carry + sd[1023];
    __syncthreads();
  }
}

__global__ __launch_bounds__(256) void k_fill(const int* __restrict__ src, const int* __restrict__ dst,
                                              int* __restrict__ fill, int* __restrict__ csr) {
  int e = blockIdx.x * 256 + threadIdx.x;
  if (e < NE) {
    int pos = atomicAdd(&fill[dst[e]], 1);
    csr[pos] = src[e];
  }
}

// ---------------- one-time: folded attention vectors + weight transposes --------------------

__global__ __launch_bounds__(256) void k_prew(const float* __restrict__ W1,
    const float* __restrict__ as1, const float* __restrict__ ad1,
    const float* __restrict__ W2,
    float* __restrict__ wsrc, float* __restrict__ wdst,
    float* __restrict__ W1T, float* __restrict__ W2T) {
  int tid = threadIdx.x;
  int k = tid >> 3, h = tid & 7;
  float s = 0.f, d = 0.f;
  #pragma unroll
  for (int f = 0; f < 32; ++f) {
    float wv = W1[k * D1 + h * 32 + f];
    s = fmaf(wv, as1[h * 32 + f], s);
    d = fmaf(wv, ad1[h * 32 + f], d);
  }
  wsrc[k * 8 + h] = s;
  wdst[k * 8 + h] = d;
  for (int i = tid; i < D1 * 32; i += 256) {
    int j = i >> 5, kk = i & 31;
    W1T[i] = W1[kk * D1 + j];          // W1T[j*32+kk]
  }
  for (int i = tid; i < 32 * D1; i += 256) {
    int f = i >> 8, kk = i & 255;
    W2T[i] = W2[kk * CD + f];          // W2T[f*256+kk]
  }
}

// ---------------- logits for all t: als/ald = x @ w~ ; t = blockIdx.x & 7 -------------------

__global__ __launch_bounds__(256) void k_logits8(const float* __restrict__ x,
    const float* __restrict__ wsrc, const float* __restrict__ wdst,
    float* __restrict__ als, float* __restrict__ ald) {
  __shared__ float xs[32 * 33];
  __shared__ float wsr[256], wdr[256];
  int tid = threadIdx.x;
  int t = blockIdx.x & 7;
  int n0 = (blockIdx.x >> 3) * 32;
  const float* xt = x + (size_t)t * NN * 32;
  int nl = tid >> 3, h = tid & 7;
  for (int i = tid; i < 1024; i += 256) {
    int g = i >> 5, k = i & 31;
    xs[g * 33 + k] = xt[n0 * 32 + i];
  }
  wsr[tid] = wsrc[tid];
  wdr[tid] = wdst[tid];
  __syncthreads();
  const float* xr = xs + nl * 33;
  float as = 0.f, ad = 0.f;
  #pragma unroll
  for (int k = 0; k < 32; ++k) {
    float xv = xr[k];
    as = fmaf(xv, wsr[k * 8 + h], as);
    ad = fmaf(xv, wdr[k * 8 + h], ad);
  }
  als[(size_t)t * NN * 8 + n0 * 8 + tid] = as;
  ald[(size_t)t * NN * 8 + n0 * 8 + tid] = ad;
}

// ---------------- layer-1 gather, ALL t in one wave: wave=node, lane=(t,h) ------------------
// One edge walk per node total (vs per-t). One exp per lane = exact (t,h) weight count.
// The 8 x-row float4 loads share a base (immediate offsets) and broadcast across h-lanes.
// No LDS, no shuffles, no spill-prone structures. Self-loop as last iteration.

__global__ __launch_bounds__(256, 4) void k_gat1(const float* __restrict__ x,
    const float* __restrict__ als, const float* __restrict__ ald,
    const int* __restrict__ rowptr, const int* __restrict__ csr,
    float* __restrict__ aggx, float* __restrict__ den1) {
  int tid = threadIdx.x;
  int wv = tid >> 6, lane = tid & 63;
  int t = lane >> 3, h = lane & 7;
  int n = blockIdx.x * 4 + wv;
  const float* alst = als + (size_t)t * NN * 8 + h;           // + s*8 per edge
  float adv = ald[(size_t)t * NN * 8 + (size_t)n * 8 + h];
  const float4* x4t = (const float4*)(x + (size_t)t * NN * 32);
  float4 acc[8];
  #pragma unroll
  for (int q = 0; q < 8; ++q) acc[q] = make_float4(0.f, 0.f, 0.f, 0.f);
  float den = 0.f;
  int beg = rowptr[n], end = rowptr[n + 1];
  int s_next = (beg < end) ? csr[beg] : n;
  for (int idx = beg; idx <= end; ++idx) {      // edges then self-loop
    int s = s_next;
    s_next = (idx + 1 < end) ? csr[idx + 1] : n;
    float a = alst[(size_t)s * 8] + adv;
    a = fmaxf(a, 0.2f * a);                     // leaky_relu(0.2), branch-free
    float e = __expf(a);
    const float4* xr = x4t + (size_t)s * 8;
    float4 v0 = xr[0], v1 = xr[1], v2 = xr[2], v3 = xr[3];
    float4 v4 = xr[4], v5 = xr[5], v6 = xr[6], v7 = xr[7];
    acc[0].x = fmaf(e, v0.x, acc[0].x); acc[0].y = fmaf(e, v0.y, acc[0].y);
    acc[0].z = fmaf(e, v0.z, acc[0].z); acc[0].w = fmaf(e, v0.w, acc[0].w);
    acc[1].x = fmaf(e, v1.x, acc[1].x); acc[1].y = fmaf(e, v1.y, acc[1].y);
    acc[1].z = fmaf(e, v1.z, acc[1].z); acc[1].w = fmaf(e, v1.w, acc[1].w);
    acc[2].x = fmaf(e, v2.x, acc[2].x); acc[2].y = fmaf(e, v2.y, acc[2].y);
    acc[2].z = fmaf(e, v2.z, acc[2].z); acc[2].w = fmaf(e, v2.w, acc[2].w);
    acc[3].x = fmaf(e, v3.x, acc[3].x); acc[3].y = fmaf(e, v3.y, acc[3].y);
    acc[3].z = fmaf(e, v3.z, acc[3].z); acc[3].w = fmaf(e, v3.w, acc[3].w);
    acc[4].x = fmaf(e, v4.x, acc[4].x); acc[4].y = fmaf(e, v4.y, acc[4].y);
    acc[4].z = fmaf(e, v4.z, acc[4].z); acc[4].w = fmaf(e, v4.w, acc[4].w);
    acc[5].x = fmaf(e, v5.x, acc[5].x); acc[5].y = fmaf(e, v5.y, acc[5].y);
    acc[5].z = fmaf(e, v5.z, acc[5].z); acc[5].w = fmaf(e, v5.w, acc[5].w);
    acc[6].x = fmaf(e, v6.x, acc[6].x); acc[6].y = fmaf(e, v6.y, acc[6].y);
    acc[6].z = fmaf(e, v6.z, acc[6].z); acc[6].w = fmaf(e, v6.w, acc[6].w);
    acc[7].x = fmaf(e, v7.x, acc[7].x); acc[7].y = fmaf(e, v7.y, acc[7].y);
    acc[7].z = fmaf(e, v7.z, acc[7].z); acc[7].w = fmaf(e, v7.w, acc[7].w);
    den += e;
  }
  // aggx[(t*NN+n)*256 + h*32 + q*4] — each lane writes 128B contiguous
  float4* ao = (float4*)(aggx + ((size_t)t * NN + n) * 256 + h * 32);
  #pragma unroll
  for (int q = 0; q < 8; ++q) ao[q] = acc[q];
  den1[((size_t)t * NN + n) * 8 + h] = den;
}

// ---------------- dense epilogue: rel1 = relu(aggx@W1/den + b1); h2 = rel1@W2; logits -------
// block = 16 nodes of one t (t = blockIdx & 7). Weight columns from W1T/W2T, staged LDS rows.

__global__ __launch_bounds__(256, 3) void k_post(const float* __restrict__ aggx,
    const float* __restrict__ den1, const float* __restrict__ W1T, const float* __restrict__ b1,
    const float* __restrict__ W2T, const float* __restrict__ as2, const float* __restrict__ ad2,
    float* __restrict__ h2, float* __restrict__ al2s, float* __restrict__ al2d) {
  __shared__ float aggs[16 * 256];
  __shared__ float dens[16 * 8];
  __shared__ float rels[16 * 256];
  __shared__ float part[4][16][32];
  int tid = threadIdx.x;
  int t = blockIdx.x & 7;
  int n0 = (blockIdx.x >> 3) * 16;

  const float4* ag4 = (const float4*)(aggx + ((size_t)t * NN + n0) * 256);
  float4* as4 = (float4*)aggs;
  for (int i = tid; i < 16 * 64; i += 256) as4[i] = ag4[i];
  if (tid < 128) dens[tid] = den1[((size_t)t * NN + n0) * 8 + tid];

  int j = tid;
  float4 w1v[8];
  const float4* w1p = (const float4*)(W1T + j * 32);
  #pragma unroll
  for (int q8 = 0; q8 < 8; ++q8) w1v[q8] = w1p[q8];
  float bj = b1[j];
  int q = tid >> 5, f = tid & 31;
  float4 w2v[8];
  const float4* w2p = (const float4*)(W2T + f * 256 + q * 32);
  #pragma unroll
  for (int q8 = 0; q8 < 8; ++q8) w2v[q8] = w2p[q8];
  float as2f = as2[f], ad2f = ad2[f];
  __syncthreads();

  // phase 2
  int hj = j >> 5;
  #pragma unroll 4
  for (int g = 0; g < 16; ++g) {
    const float4* ar4 = (const float4*)(aggs + g * 256 + hj * 32);
    float a = 0.f;
    #pragma unroll
    for (int k4 = 0; k4 < 8; ++k4) {
      float4 av = ar4[k4];
      a = fmaf(av.x, w1v[k4].x, fmaf(av.y, w1v[k4].y,
          fmaf(av.z, w1v[k4].z, fmaf(av.w, w1v[k4].w, a))));
    }
    float v = fmaf(a, 1.f / dens[g * 8 + hj], bj);
    rels[g * 256 + j] = fmaxf(v, 0.f);
  }
  __syncthreads();

  // phase 3 (k-split over q, shuffle + LDS reduce)
  float accg[16];
  #pragma unroll 4
  for (int g = 0; g < 16; ++g) {
    const float4* r4 = (const float4*)(rels + g * 256 + q * 32);
    float a = 0.f;
    #pragma unroll
    for (int jj = 0; jj < 8; ++jj) {
      float4 a4 = r4[jj];
      a = fmaf(a4.x, w2v[jj].x, fmaf(a4.y, w2v[jj].y,
          fmaf(a4.z, w2v[jj].z, fmaf(a4.w, w2v[jj].w, a))));
    }
    a += __shfl_xor(a, 32, 64);
    accg[g] = a;
  }
  int wv = tid >> 6;
  if ((tid & 32) == 0) {
    #pragma unroll
    for (int g = 0; g < 16; ++g) part[wv][g][f] = accg[g];
  }
  __syncthreads();

  {
    int g = tid >> 5, ff = tid & 31;
    #pragma unroll
    for (int rep = 0; rep < 2; ++rep) {
      int gg = g + rep * 8;
      float v = part[0][gg][ff] + part[1][gg][ff] + part[2][gg][ff] + part[3][gg][ff];
      int nn = n0 + gg;
      h2[((size_t)t * NN + nn) * CD + ff] = v;
      float vs = v * as2f, vd = v * ad2f;
      #pragma unroll
      for (int m = 1; m < 32; m <<= 1) {
        vs += __shfl_xor(vs, m, 64);
        vd += __shfl_xor(vd, m, 64);
      }
      if (ff == 0) {
        al2s[(size_t)t * NN + nn] = vs;
        al2d[(size_t)t * NN + nn] = vd;
      }
    }
  }
}

// ---------------- layer-2 aggregation, ALL t in one wave: lane=(t, f-quad) ------------------
// One edge walk per node. exp redundant x8 (cheap); h2 row gather: 64 lanes = 8 rows x 128B.

__global__ __launch_bounds__(256, 8) void k_agg2(const float* __restrict__ h2,
    const float* __restrict__ al2s, const float* __restrict__ al2d,
    const int* __restrict__ rowptr, const int* __restrict__ csr,
    const float* __restrict__ b2, float* __restrict__ out) {
  int tid = threadIdx.x;
  int wv = tid >> 6, lane = tid & 63;
  int t = lane >> 3, p = lane & 7;
  int n = blockIdx.x * 4 + wv;
  const float* alst = al2s + (size_t)t * NN;
  float adv = al2d[(size_t)t * NN + n];
  const float4* h24 = (const float4*)h2 + (size_t)t * NN * 8 + p;
  float4 b4 = ((const float4*)b2)[p];
  float4 acc = make_float4(0.f, 0.f, 0.f, 0.f);
  float den = 0.f;
  int beg = rowptr[n], end = rowptr[n + 1];
  int s_next = (beg < end) ? csr[beg] : n;
  for (int idx = beg; idx <= end; ++idx) {      // edges then self-loop
    int s = s_next;
    s_next = (idx + 1 < end) ? csr[idx + 1] : n;
    float a = alst[s] + adv;
    a = fmaxf(a, 0.2f * a);
    float e = __expf(a);
    float4 v = h24[(size_t)s * 8];
    acc.x = fmaf(e, v.x, acc.x);
    acc.y = fmaf(e, v.y, acc.y);
    acc.z = fmaf(e, v.z, acc.z);
    acc.w = fmaf(e, v.w, acc.w);
    den += e;
  }
  float inv = 1.f / den;
  float4 o;
  o.x = fmaf(acc.x, inv, b4.x);
  o.y = fmaf(acc.y, inv, b4.y);
  o.z = fmaf(acc.z, inv, b4.z);
  o.w = fmaf(acc.w, inv, b4.w);
  ((float4*)out)[((size_t)t * NN + n) * 8 + p] = o;
}

// ---------------- LSTM, all t in one kernel: weights in VGPRs, h/c in LDS ------------------

__global__ __launch_bounds__(256) void k_lstm_all(const float* __restrict__ agg2o,
    const float* __restrict__ w_ih, const float* __restrict__ w_hh,
    const float* __restrict__ b_ih, const float* __restrict__ b_hh,
    float* __restrict__ out) {
  __shared__ float xs[16 * 32], hs[16 * 32], cs[16 * 32], pre[16 * 128];
  int tid = threadIdx.x;
  int slot = tid >> 7;
  int r = tid & 127;
  float4 wi[8], wh[8];
  const float4* wi4 = (const float4*)(w_ih + r * 32);
  const float4* wh4 = (const float4*)(w_hh + r * 32);
  #pragma unroll
  for (int q = 0; q < 8; ++q) { wi[q] = wi4[q]; wh[q] = wh4[q]; }
  float bias = b_ih[r] + b_hh[r];
  int base = blockIdx.x * 16;
  for (int i = tid; i < 512; i += 256) { hs[i] = 0.f; cs[i] = 0.f; }
  for (int t = 0; t < TT; ++t) {
    for (int i = tid; i < 512; i += 256) xs[i] = agg2o[(size_t)t * NN * 32 + base * 32 + i];
    __syncthreads();
    #pragma unroll
    for (int g = 0; g < 8; ++g) {
      int nl = slot * 8 + g;
      const float4* xv4 = (const float4*)(xs + nl * 32);
      const float4* hv4 = (const float4*)(hs + nl * 32);
      float acc = bias;
      #pragma unroll
      for (int q = 0; q < 8; ++q) {
        float4 a = xv4[q], b = hv4[q];
        acc = fmaf(a.x, wi[q].x, acc);
        acc = fmaf(a.y, wi[q].y, acc);
        acc = fmaf(a.z, wi[q].z, acc);
        acc = fmaf(a.w, wi[q].w, acc);
        acc = fmaf(b.x, wh[q].x, acc);
        acc = fmaf(b.y, wh[q].y, acc);
        acc = fmaf(b.z, wh[q].z, acc);
        acc = fmaf(b.w, wh[q].w, acc);
      }
      pre[nl * 128 + r] = acc;
    }
    __syncthreads();
    for (int i = tid; i < 512; i += 256) {
      int nl = i >> 5, k = i & 31;
      float ai = pre[nl * 128 + k];
      float af = pre[nl * 128 + 32 + k];
      float ag = pre[nl * 128 + 64 + k];
      float ao = pre[nl * 128 + 96 + k];
      float ii = 1.f / (1.f + __expf(-ai));
      float ff = 1.f / (1.f + __expf(-af));
      float gg = tanhf(ag);
      float oo = 1.f / (1.f + __expf(-ao));
      float cn = fmaf(ff, cs[i], ii * gg);
      float hn = oo * tanhf(cn);
      cs[i] = cn; hs[i] = hn;
      out[(size_t)t * NN * 32 + base * 32 + i] = hn;
    }
  }
}

// ---------------- softmax over nodes, coalesced two-pass ----------------

__global__ __launch_bounds__(256) void k_sm_sum(const float* __restrict__ out, float* __restrict__ sums) {
  int t = blockIdx.y;
  const float4* b4 = (const float4*)(out + ((size_t)t * NN + blockIdx.x * 800) * CD);
  int tid = threadIdx.x;
  float4 s4 = make_float4(0.f, 0.f, 0.f, 0.f);
  for (int i = tid; i < 6400; i += 256) {
    float4 v = b4[i];
    s4.x += __expf(v.x); s4.y += __expf(v.y);
    s4.z += __expf(v.z); s4.w += __expf(v.w);
  }
  __shared__ float4 red[256];
  red[tid] = s4;
  __syncthreads();
  for (int off = 128; off >= 8; off >>= 1) {
    if (tid < off) {
      float4 o = red[tid + off];
      red[tid].x += o.x; red[tid].y += o.y; red[tid].z += o.z; red[tid].w += o.w;
    }
    __syncthreads();
  }
  if (tid < 8) {
    float4 v = red[tid];
    int c0 = tid * 4;
    atomicAdd(&sums[t * CD + c0 + 0], v.x);
    atomicAdd(&sums[t * CD + c0 + 1], v.y);
    atomicAdd(&sums[t * CD + c0 + 2], v.z);
    atomicAdd(&sums[t * CD + c0 + 3], v.w);
  }
}

__global__ __launch_bounds__(256) void k_sm_scale(float* __restrict__ out, const float* __restrict__ sums) {
  int t = blockIdx.y;
  __shared__ float inv[CD];
  int tid = threadIdx.x;
  if (tid < CD) inv[tid] = 1.f / sums[t * CD + tid];
  __syncthreads();
  float4* b4 = (float4*)(out + ((size_t)t * NN + blockIdx.x * 800) * CD);
  for (int i = tid; i < 6400; i += 256) {
    float4 v = b4[i];
    int c0 = (4 * i) & 31;
    v.x = __expf(v.x) * inv[c0];
    v.y = __expf(v.y) * inv[c0 + 1];
    v.z = __expf(v.z) * inv[c0 + 2];
    v.w = __expf(v.w) * inv[c0 + 3];
    b4[i] = v;
  }
}

// ---------------- launch ----------------

extern "C" void kernel_launch(void* const* d_in, const int* in_sizes, int n_in,
                              void* d_out, int out_size, void* d_ws, size_t ws_size,
                              hipStream_t stream) {
  const float* x   = (const float*)d_in[0];
  const float* W1  = (const float*)d_in[1];
  const float* as1 = (const float*)d_in[2];
  const float* ad1 = (const float*)d_in[3];
  const float* b1  = (const float*)d_in[4];
  const float* W2  = (const float*)d_in[5];
  const float* as2 = (const float*)d_in[6];
  const float* ad2 = (const float*)d_in[7];
  const float* b2  = (const float*)d_in[8];
  const float* wih = (const float*)d_in[9];
  const float* whh = (const float*)d_in[10];
  const float* bih = (const float*)d_in[11];
  const float* bhh = (const float*)d_in[12];
  const int*   ei  = (const int*)d_in[13];
  const int* srcp = ei;
  const int* dstp = ei + NE;
  float* out = (float*)d_out;

  float* ws = (float*)d_ws;
  float* aggx  = ws;  ws += (size_t)TT * NN * 256;   // 164 MB
  float* den1  = ws;  ws += (size_t)TT * NN * 8;
  float* al1s  = ws;  ws += (size_t)TT * NN * 8;
  float* al1d  = ws;  ws += (size_t)TT * NN * 8;
  float* h2    = ws;  ws += (size_t)TT * NN * CD;
  float* al2s  = ws;  ws += (size_t)TT * NN;
  float* al2d  = ws;  ws += (size_t)TT * NN;
  float* agg2o = ws;  ws += (size_t)TT * NN * CD;
  float* sums  = ws;  ws += TT * CD;
  float* wsrc  = ws;  ws += 256;
  float* wdst  = ws;  ws += 256;
  float* W1T   = ws;  ws += D1 * 32;
  float* W2T   = ws;  ws += 32 * D1;
  int* rowptr = (int*)ws;
  int* fill   = rowptr + NN + 1;
  int* csr    = fill + NN;
  int* deg    = csr + NE;

  hipMemsetAsync(sums, 0, TT * CD * sizeof(float), stream);
  hipMemsetAsync(deg, 0, NN * sizeof(int), stream);

  k_deg<<<(NE + 255) / 256, 256, 0, stream>>>(dstp, deg);
  k_scan<<<1, 1024, 0, stream>>>(deg, rowptr, fill);
  k_fill<<<(NE + 255) / 256, 256, 0, stream>>>(srcp, dstp, fill, csr);
  k_prew<<<1, 256, 0, stream>>>(W1, as1, ad1, W2, wsrc, wdst, W1T, W2T);

  k_logits8<<<(NN / 32) * TT, 256, 0, stream>>>(x, wsrc, wdst, al1s, al1d);
  k_gat1<<<NN / 4, 256, 0, stream>>>(x, al1s, al1d, rowptr, csr, aggx, den1);
  k_post<<<(NN / 16) * TT, 256, 0, stream>>>(aggx, den1, W1T, b1, W2T, as2, ad2,
                                             h2, al2s, al2d);
  k_agg2<<<NN / 4, 256, 0, stream>>>(h2, al2s, al2d, rowptr, csr, b2, agg2o);
  k_lstm_all<<<NN / 16, 256, 0, stream>>>(agg2o, wih, whh, bih, bhh, out);

  k_sm_sum<<<dim3(25, TT), 256, 0, stream>>>(out, sums);
  k_sm_scale<<<dim3(25, TT), 256, 0, stream>>>(out, sums);
}

// Round 10
// 637.760 us; speedup vs baseline: 1.3194x; 1.0025x over previous
//
#include <hip/hip_runtime.h>
#include <math.h>

#define NN 20000   // nodes
#define NE 320000  // edges (without self-loops)
#define TT 8       // timesteps
#define D1 256     // H*F layer-1 width
#define CD 32      // layer-2 width == LSTM hidden

// ---------------- CSR build (once per launch; edges identical across t) ----------------

__global__ __launch_bounds__(256) void k_deg(const int* __restrict__ dst, int* __restrict__ deg) {
  int e = blockIdx.x * 256 + threadIdx.x;
  if (e < NE) atomicAdd(&deg[dst[e]], 1);
}

__global__ __launch_bounds__(1024) void k_scan(const int* __restrict__ deg,
                                               int* __restrict__ rowptr, int* __restrict__ fill) {
  __shared__ int sd[1024];
  __shared__ int carry_s;
  int tid = threadIdx.x;
  if (tid == 0) { carry_s = 0; rowptr[0] = 0; }
  __syncthreads();
  for (int base = 0; base < NN; base += 1024) {
    int i = base + tid;
    int v = (i < NN) ? deg[i] : 0;
    sd[tid] = v;
    __syncthreads();
    for (int off = 1; off < 1024; off <<= 1) {
      int t = (tid >= off) ? sd[tid - off] : 0;
      __syncthreads();
      sd[tid] += t;
      __syncthreads();
    }
    int incl = sd[tid];
    int carry = carry_s;
    if (i < NN) { rowptr[i + 1] = carry + incl; fill[i] = carry + incl - v; }
    __syncthreads();
    if (tid == 1023) carry_s = carry + sd[1023];
    __syncthreads();
  }
}

__global__ __launch_bounds__(256) void k_fill(const int* __restrict__ src, const int* __restrict__ dst,
                                              int* __restrict__ fill, int* __restrict__ csr) {
  int e = blockIdx.x * 256 + threadIdx.x;
  if (e < NE) {
    int pos = atomicAdd(&fill[dst[e]], 1);
    csr[pos] = src[e];
  }
}

// ---------------- one-time: folded attention vectors + weight transposes --------------------

__global__ __launch_bounds__(256) void k_prew(const float* __restrict__ W1,
    const float* __restrict__ as1, const float* __restrict__ ad1,
    const float* __restrict__ W2,
    float* __restrict__ wsrc, float* __restrict__ wdst,
    float* __restrict__ W1T, float* __restrict__ W2T) {
  int tid = threadIdx.x;
  int k = tid >> 3, h = tid & 7;
  float s = 0.f, d = 0.f;
  #pragma unroll
  for (int f = 0; f < 32; ++f) {
    float wv = W1[k * D1 + h * 32 + f];
    s = fmaf(wv, as1[h * 32 + f], s);
    d = fmaf(wv, ad1[h * 32 + f], d);
  }
  wsrc[k * 8 + h] = s;
  wdst[k * 8 + h] = d;
  for (int i = tid; i < D1 * 32; i += 256) {
    int j = i >> 5, kk = i & 31;
    W1T[i] = W1[kk * D1 + j];          // W1T[j*32+kk]
  }
  for (int i = tid; i < 32 * D1; i += 256) {
    int f = i >> 8, kk = i & 255;
    W2T[i] = W2[kk * CD + f];          // W2T[f*256+kk]
  }
}

// ---------------- logits for all t: als/ald = x @ w~ ; t = blockIdx.x & 7 -------------------

__global__ __launch_bounds__(256) void k_logits8(const float* __restrict__ x,
    const float* __restrict__ wsrc, const float* __restrict__ wdst,
    float* __restrict__ als, float* __restrict__ ald) {
  __shared__ float xs[32 * 33];
  __shared__ float wsr[256], wdr[256];
  int tid = threadIdx.x;
  int t = blockIdx.x & 7;
  int n0 = (blockIdx.x >> 3) * 32;
  const float* xt = x + (size_t)t * NN * 32;
  int nl = tid >> 3, h = tid & 7;
  for (int i = tid; i < 1024; i += 256) {
    int g = i >> 5, k = i & 31;
    xs[g * 33 + k] = xt[n0 * 32 + i];
  }
  wsr[tid] = wsrc[tid];
  wdr[tid] = wdst[tid];
  __syncthreads();
  const float* xr = xs + nl * 33;
  float as = 0.f, ad = 0.f;
  #pragma unroll
  for (int k = 0; k < 32; ++k) {
    float xv = xr[k];
    as = fmaf(xv, wsr[k * 8 + h], as);
    ad = fmaf(xv, wdr[k * 8 + h], ad);
  }
  als[(size_t)t * NN * 8 + n0 * 8 + tid] = as;
  ald[(size_t)t * NN * 8 + n0 * 8 + tid] = ad;
}

// ---------------- layer-1 gather, ALL t in one wave: wave=node, lane=(t,h), 2-edge unroll ---

__global__ __launch_bounds__(256, 4) void k_gat1(const float* __restrict__ x,
    const float* __restrict__ als, const float* __restrict__ ald,
    const int* __restrict__ rowptr, const int* __restrict__ csr,
    float* __restrict__ aggx, float* __restrict__ den1) {
  int tid = threadIdx.x;
  int wv = tid >> 6, lane = tid & 63;
  int t = lane >> 3, h = lane & 7;
  int n = blockIdx.x * 4 + wv;
  const float* alst = als + (size_t)t * NN * 8 + h;           // + s*8 per edge
  float adv = ald[(size_t)t * NN * 8 + (size_t)n * 8 + h];
  const float4* x4t = (const float4*)(x + (size_t)t * NN * 32);
  float4 acc[8];
  #pragma unroll
  for (int q = 0; q < 8; ++q) acc[q] = make_float4(0.f, 0.f, 0.f, 0.f);
  float den = 0.f;
  int beg = rowptr[n], end = rowptr[n + 1];
  // virtual list [beg, end]: edges then self-loop at position `end`
  int v = beg;
  for (; v + 1 <= end; v += 2) {
    int s0 = csr[v];                              // v < end guaranteed here
    int s1 = (v + 1 < end) ? csr[v + 1] : n;
    float a0 = alst[(size_t)s0 * 8] + adv;
    float a1 = alst[(size_t)s1 * 8] + adv;
    const float4* xr0 = x4t + (size_t)s0 * 8;
    const float4* xr1 = x4t + (size_t)s1 * 8;
    a0 = fmaxf(a0, 0.2f * a0);
    a1 = fmaxf(a1, 0.2f * a1);
    float e0 = __expf(a0), e1 = __expf(a1);
    float4 u0 = xr0[0], u1 = xr0[1], u2 = xr0[2], u3 = xr0[3];
    float4 u4 = xr0[4], u5 = xr0[5], u6 = xr0[6], u7 = xr0[7];
    float4 w0 = xr1[0], w1 = xr1[1], w2 = xr1[2], w3 = xr1[3];
    float4 w4 = xr1[4], w5 = xr1[5], w6 = xr1[6], w7 = xr1[7];
    acc[0].x = fmaf(e1, w0.x, fmaf(e0, u0.x, acc[0].x));
    acc[0].y = fmaf(e1, w0.y, fmaf(e0, u0.y, acc[0].y));
    acc[0].z = fmaf(e1, w0.z, fmaf(e0, u0.z, acc[0].z));
    acc[0].w = fmaf(e1, w0.w, fmaf(e0, u0.w, acc[0].w));
    acc[1].x = fmaf(e1, w1.x, fmaf(e0, u1.x, acc[1].x));
    acc[1].y = fmaf(e1, w1.y, fmaf(e0, u1.y, acc[1].y));
    acc[1].z = fmaf(e1, w1.z, fmaf(e0, u1.z, acc[1].z));
    acc[1].w = fmaf(e1, w1.w, fmaf(e0, u1.w, acc[1].w));
    acc[2].x = fmaf(e1, w2.x, fmaf(e0, u2.x, acc[2].x));
    acc[2].y = fmaf(e1, w2.y, fmaf(e0, u2.y, acc[2].y));
    acc[2].z = fmaf(e1, w2.z, fmaf(e0, u2.z, acc[2].z));
    acc[2].w = fmaf(e1, w2.w, fmaf(e0, u2.w, acc[2].w));
    acc[3].x = fmaf(e1, w3.x, fmaf(e0, u3.x, acc[3].x));
    acc[3].y = fmaf(e1, w3.y, fmaf(e0, u3.y, acc[3].y));
    acc[3].z = fmaf(e1, w3.z, fmaf(e0, u3.z, acc[3].z));
    acc[3].w = fmaf(e1, w3.w, fmaf(e0, u3.w, acc[3].w));
    acc[4].x = fmaf(e1, w4.x, fmaf(e0, u4.x, acc[4].x));
    acc[4].y = fmaf(e1, w4.y, fmaf(e0, u4.y, acc[4].y));
    acc[4].z = fmaf(e1, w4.z, fmaf(e0, u4.z, acc[4].z));
    acc[4].w = fmaf(e1, w4.w, fmaf(e0, u4.w, acc[4].w));
    acc[5].x = fmaf(e1, w5.x, fmaf(e0, u5.x, acc[5].x));
    acc[5].y = fmaf(e1, w5.y, fmaf(e0, u5.y, acc[5].y));
    acc[5].z = fmaf(e1, w5.z, fmaf(e0, u5.z, acc[5].z));
    acc[5].w = fmaf(e1, w5.w, fmaf(e0, u5.w, acc[5].w));
    acc[6].x = fmaf(e1, w6.x, fmaf(e0, u6.x, acc[6].x));
    acc[6].y = fmaf(e1, w6.y, fmaf(e0, u6.y, acc[6].y));
    acc[6].z = fmaf(e1, w6.z, fmaf(e0, u6.z, acc[6].z));
    acc[6].w = fmaf(e1, w6.w, fmaf(e0, u6.w, acc[6].w));
    acc[7].x = fmaf(e1, w7.x, fmaf(e0, u7.x, acc[7].x));
    acc[7].y = fmaf(e1, w7.y, fmaf(e0, u7.y, acc[7].y));
    acc[7].z = fmaf(e1, w7.z, fmaf(e0, u7.z, acc[7].z));
    acc[7].w = fmaf(e1, w7.w, fmaf(e0, u7.w, acc[7].w));
    den += e0 + e1;
  }
  if (v <= end) {                                 // 1 leftover (edge or self-loop)
    int s = (v < end) ? csr[v] : n;
    float a = alst[(size_t)s * 8] + adv;
    a = fmaxf(a, 0.2f * a);
    float e = __expf(a);
    const float4* xr = x4t + (size_t)s * 8;
    #pragma unroll
    for (int q = 0; q < 8; ++q) {
      float4 xv = xr[q];
      acc[q].x = fmaf(e, xv.x, acc[q].x);
      acc[q].y = fmaf(e, xv.y, acc[q].y);
      acc[q].z = fmaf(e, xv.z, acc[q].z);
      acc[q].w = fmaf(e, xv.w, acc[q].w);
    }
    den += e;
  }
  float4* ao = (float4*)(aggx + ((size_t)t * NN + n) * 256 + h * 32);
  #pragma unroll
  for (int q = 0; q < 8; ++q) ao[q] = acc[q];
  den1[((size_t)t * NN + n) * 8 + h] = den;
}

// ---------------- dense epilogue: 2-col register blocking, part aliased on aggs -------------
// block = 16 nodes of one t. LDS 33 KB -> 4 blocks/CU. DS reads halved vs 1-col version.

__global__ __launch_bounds__(256, 4) void k_post(const float* __restrict__ aggx,
    const float* __restrict__ den1, const float* __restrict__ W1T, const float* __restrict__ b1,
    const float* __restrict__ W2T, const float* __restrict__ as2, const float* __restrict__ ad2,
    float* __restrict__ h2, float* __restrict__ al2s, float* __restrict__ al2d) {
  __shared__ float aggs[16 * 256];   // phase-2 input; aliased as part[8][16][32] in phase 3
  __shared__ float rels[16 * 256];
  __shared__ float dens[16 * 8];     // INVERSE denominators
  float* part = aggs;                // 8*16*32 == 16*256 floats exactly
  int tid = threadIdx.x;
  int t = blockIdx.x & 7;
  int n0 = (blockIdx.x >> 3) * 16;

  const float4* ag4 = (const float4*)(aggx + ((size_t)t * NN + n0) * 256);
  float4* as4 = (float4*)aggs;
  #pragma unroll
  for (int k = 0; k < 4; ++k) as4[tid + k * 256] = ag4[tid + k * 256];
  if (tid < 128) dens[tid] = 1.f / den1[((size_t)t * NN + n0) * 8 + tid];

  int u = tid & 127, grp = tid >> 7;
  int j0 = 2 * u;
  int hj = j0 >> 5;
  float4 w1a[8], w1b[8];
  const float4* w1p = (const float4*)(W1T + j0 * 32);
  #pragma unroll
  for (int q8 = 0; q8 < 8; ++q8) { w1a[q8] = w1p[q8]; w1b[q8] = w1p[q8 + 8]; }
  float bj0 = b1[j0], bj1 = b1[j0 + 1];
  __syncthreads();

  // phase 2: rows grp*8..+7, columns j0, j0+1 (aggs reads shared by both columns)
  #pragma unroll
  for (int g = 0; g < 8; ++g) {
    int row = grp * 8 + g;
    const float4* ar4 = (const float4*)(aggs + row * 256 + hj * 32);
    float a0 = 0.f, a1 = 0.f;
    #pragma unroll
    for (int k4 = 0; k4 < 8; ++k4) {
      float4 av = ar4[k4];
      a0 = fmaf(av.x, w1a[k4].x, fmaf(av.y, w1a[k4].y,
           fmaf(av.z, w1a[k4].z, fmaf(av.w, w1a[k4].w, a0))));
      a1 = fmaf(av.x, w1b[k4].x, fmaf(av.y, w1b[k4].y,
           fmaf(av.z, w1b[k4].z, fmaf(av.w, w1b[k4].w, a1))));
    }
    float invd = dens[row * 8 + hj];
    float2 r;
    r.x = fmaxf(fmaf(a0, invd, bj0), 0.f);
    r.y = fmaxf(fmaf(a1, invd, bj1), 0.f);
    *(float2*)(rels + row * 256 + j0) = r;
  }
  __syncthreads();   // rels ready; aggs dead -> reuse as part

  // phase 3: q-split over K (8 chunks of 32), columns f0, f0+1
  int q = u >> 4, fp = u & 15, f0 = 2 * fp;
  float4 w2a[8], w2b[8];
  const float4* w2pa = (const float4*)(W2T + f0 * 256 + q * 32);
  const float4* w2pb = (const float4*)(W2T + (f0 + 1) * 256 + q * 32);
  #pragma unroll
  for (int q8 = 0; q8 < 8; ++q8) { w2a[q8] = w2pa[q8]; w2b[q8] = w2pb[q8]; }
  #pragma unroll
  for (int g = 0; g < 8; ++g) {
    int row = grp * 8 + g;
    const float4* r4 = (const float4*)(rels + row * 256 + q * 32);
    float a0 = 0.f, a1 = 0.f;
    #pragma unroll
    for (int jj = 0; jj < 8; ++jj) {
      float4 a4 = r4[jj];
      a0 = fmaf(a4.x, w2a[jj].x, fmaf(a4.y, w2a[jj].y,
           fmaf(a4.z, w2a[jj].z, fmaf(a4.w, w2a[jj].w, a0))));
      a1 = fmaf(a4.x, w2b[jj].x, fmaf(a4.y, w2b[jj].y,
           fmaf(a4.z, w2b[jj].z, fmaf(a4.w, w2b[jj].w, a1))));
    }
    float2 pr; pr.x = a0; pr.y = a1;
    *(float2*)(part + q * 512 + row * 32 + f0) = pr;
  }
  __syncthreads();

  // reduce over q + h2 write + layer-2 logits
  float as2f = as2[tid & 31], ad2f = ad2[tid & 31];
  #pragma unroll
  for (int rep = 0; rep < 2; ++rep) {
    int row = (tid >> 5) + rep * 8;
    int ff = tid & 31;
    float v = 0.f;
    #pragma unroll
    for (int qq = 0; qq < 8; ++qq) v += part[qq * 512 + row * 32 + ff];
    int nn = n0 + row;
    h2[((size_t)t * NN + nn) * CD + ff] = v;
    float vs = v * as2f, vd = v * ad2f;
    #pragma unroll
    for (int m = 1; m < 32; m <<= 1) {
      vs += __shfl_xor(vs, m, 64);
      vd += __shfl_xor(vd, m, 64);
    }
    if (ff == 0) {
      al2s[(size_t)t * NN + nn] = vs;
      al2d[(size_t)t * NN + nn] = vd;
    }
  }
}

// ---------------- layer-2 aggregation, ALL t in one wave: lane=(t, f-quad), 2-edge unroll ---

__global__ __launch_bounds__(256, 8) void k_agg2(const float* __restrict__ h2,
    const float* __restrict__ al2s, const float* __restrict__ al2d,
    const int* __restrict__ rowptr, const int* __restrict__ csr,
    const float* __restrict__ b2, float* __restrict__ out) {
  int tid = threadIdx.x;
  int wv = tid >> 6, lane = tid & 63;
  int t = lane >> 3, p = lane & 7;
  int n = blockIdx.x * 4 + wv;
  const float* alst = al2s + (size_t)t * NN;
  float adv = al2d[(size_t)t * NN + n];
  const float4* h24 = (const float4*)h2 + (size_t)t * NN * 8 + p;
  float4 b4 = ((const float4*)b2)[p];
  float4 acc = make_float4(0.f, 0.f, 0.f, 0.f);
  float den = 0.f;
  int beg = rowptr[n], end = rowptr[n + 1];
  int v = beg;
  for (; v + 1 <= end; v += 2) {
    int s0 = csr[v];
    int s1 = (v + 1 < end) ? csr[v + 1] : n;
    float a0 = alst[s0] + adv;
    float a1 = alst[s1] + adv;
    float4 u = h24[(size_t)s0 * 8];
    float4 w = h24[(size_t)s1 * 8];
    a0 = fmaxf(a0, 0.2f * a0);
    a1 = fmaxf(a1, 0.2f * a1);
    float e0 = __expf(a0), e1 = __expf(a1);
    acc.x = fmaf(e1, w.x, fmaf(e0, u.x, acc.x));
    acc.y = fmaf(e1, w.y, fmaf(e0, u.y, acc.y));
    acc.z = fmaf(e1, w.z, fmaf(e0, u.z, acc.z));
    acc.w = fmaf(e1, w.w, fmaf(e0, u.w, acc.w));
    den += e0 + e1;
  }
  if (v <= end) {
    int s = (v < end) ? csr[v] : n;
    float a = alst[s] + adv;
    a = fmaxf(a, 0.2f * a);
    float e = __expf(a);
    float4 u = h24[(size_t)s * 8];
    acc.x = fmaf(e, u.x, acc.x);
    acc.y = fmaf(e, u.y, acc.y);
    acc.z = fmaf(e, u.z, acc.z);
    acc.w = fmaf(e, u.w, acc.w);
    den += e;
  }
  float inv = 1.f / den;
  float4 o;
  o.x = fmaf(acc.x, inv, b4.x);
  o.y = fmaf(acc.y, inv, b4.y);
  o.z = fmaf(acc.z, inv, b4.z);
  o.w = fmaf(acc.w, inv, b4.w);
  ((float4*)out)[((size_t)t * NN + n) * 8 + p] = o;
}

// ---------------- LSTM, all t in one kernel: weights in VGPRs, h/c in LDS ------------------

__global__ __launch_bounds__(256) void k_lstm_all(const float* __restrict__ agg2o,
    const float* __restrict__ w_ih, const float* __restrict__ w_hh,
    const float* __restrict__ b_ih, const float* __restrict__ b_hh,
    float* __restrict__ out) {
  __shared__ float xs[16 * 32], hs[16 * 32], cs[16 * 32], pre[16 * 128];
  int tid = threadIdx.x;
  int slot = tid >> 7;
  int r = tid & 127;
  float4 wi[8], wh[8];
  const float4* wi4 = (const float4*)(w_ih + r * 32);
  const float4* wh4 = (const float4*)(w_hh + r * 32);
  #pragma unroll
  for (int q = 0; q < 8; ++q) { wi[q] = wi4[q]; wh[q] = wh4[q]; }
  float bias = b_ih[r] + b_hh[r];
  int base = blockIdx.x * 16;
  for (int i = tid; i < 512; i += 256) { hs[i] = 0.f; cs[i] = 0.f; }
  for (int t = 0; t < TT; ++t) {
    for (int i = tid; i < 512; i += 256) xs[i] = agg2o[(size_t)t * NN * 32 + base * 32 + i];
    __syncthreads();
    #pragma unroll
    for (int g = 0; g < 8; ++g) {
      int nl = slot * 8 + g;
      const float4* xv4 = (const float4*)(xs + nl * 32);
      const float4* hv4 = (const float4*)(hs + nl * 32);
      float acc = bias;
      #pragma unroll
      for (int q = 0; q < 8; ++q) {
        float4 a = xv4[q], b = hv4[q];
        acc = fmaf(a.x, wi[q].x, acc);
        acc = fmaf(a.y, wi[q].y, acc);
        acc = fmaf(a.z, wi[q].z, acc);
        acc = fmaf(a.w, wi[q].w, acc);
        acc = fmaf(b.x, wh[q].x, acc);
        acc = fmaf(b.y, wh[q].y, acc);
        acc = fmaf(b.z, wh[q].z, acc);
        acc = fmaf(b.w, wh[q].w, acc);
      }
      pre[nl * 128 + r] = acc;
    }
    __syncthreads();
    for (int i = tid; i < 512; i += 256) {
      int nl = i >> 5, k = i & 31;
      float ai = pre[nl * 128 + k];
      float af = pre[nl * 128 + 32 + k];
      float ag = pre[nl * 128 + 64 + k];
      float ao = pre[nl * 128 + 96 + k];
      float ii = 1.f / (1.f + __expf(-ai));
      float ff = 1.f / (1.f + __expf(-af));
      float gg = tanhf(ag);
      float oo = 1.f / (1.f + __expf(-ao));
      float cn = fmaf(ff, cs[i], ii * gg);
      float hn = oo * tanhf(cn);
      cs[i] = cn; hs[i] = hn;
      out[(size_t)t * NN * 32 + base * 32 + i] = hn;
    }
  }
}

// ---------------- softmax over nodes, coalesced two-pass ----------------

__global__ __launch_bounds__(256) void k_sm_sum(const float* __restrict__ out, float* __restrict__ sums) {
  int t = blockIdx.y;
  const float4* b4 = (const float4*)(out + ((size_t)t * NN + blockIdx.x * 800) * CD);
  int tid = threadIdx.x;
  float4 s4 = make_float4(0.f, 0.f, 0.f, 0.f);
  for (int i = tid; i < 6400; i += 256) {
    float4 v = b4[i];
    s4.x += __expf(v.x); s4.y += __expf(v.y);
    s4.z += __expf(v.z); s4.w += __expf(v.w);
  }
  __shared__ float4 red[256];
  red[tid] = s4;
  __syncthreads();
  for (int off = 128; off >= 8; off >>= 1) {
    if (tid < off) {
      float4 o = red[tid + off];
      red[tid].x += o.x; red[tid].y += o.y; red[tid].z += o.z; red[tid].w += o.w;
    }
    __syncthreads();
  }
  if (tid < 8) {
    float4 v = red[tid];
    int c0 = tid * 4;
    atomicAdd(&sums[t * CD + c0 + 0], v.x);
    atomicAdd(&sums[t * CD + c0 + 1], v.y);
    atomicAdd(&sums[t * CD + c0 + 2], v.z);
    atomicAdd(&sums[t * CD + c0 + 3], v.w);
  }
}

__global__ __launch_bounds__(256) void k_sm_scale(float* __restrict__ out, const float* __restrict__ sums) {
  int t = blockIdx.y;
  __shared__ float inv[CD];
  int tid = threadIdx.x;
  if (tid < CD) inv[tid] = 1.f / sums[t * CD + tid];
  __syncthreads();
  float4* b4 = (float4*)(out + ((size_t)t * NN + blockIdx.x * 800) * CD);
  for (int i = tid; i < 6400; i += 256) {
    float4 v = b4[i];
    int c0 = (4 * i) & 31;
    v.x = __expf(v.x) * inv[c0];
    v.y = __expf(v.y) * inv[c0 + 1];
    v.z = __expf(v.z) * inv[c0 + 2];
    v.w = __expf(v.w) * inv[c0 + 3];
    b4[i] = v;
  }
}

// ---------------- launch ----------------

extern "C" void kernel_launch(void* const* d_in, const int* in_sizes, int n_in,
                              void* d_out, int out_size, void* d_ws, size_t ws_size,
                              hipStream_t stream) {
  const float* x   = (const float*)d_in[0];
  const float* W1  = (const float*)d_in[1];
  const float* as1 = (const float*)d_in[2];
  const float* ad1 = (const float*)d_in[3];
  const float* b1  = (const float*)d_in[4];
  const float* W2  = (const float*)d_in[5];
  const float* as2 = (const float*)d_in[6];
  const float* ad2 = (const float*)d_in[7];
  const float* b2  = (const float*)d_in[8];
  const float* wih = (const float*)d_in[9];
  const float* whh = (const float*)d_in[10];
  const float* bih = (const float*)d_in[11];
  const float* bhh = (const float*)d_in[12];
  const int*   ei  = (const int*)d_in[13];
  const int* srcp = ei;
  const int* dstp = ei + NE;
  float* out = (float*)d_out;

  float* ws = (float*)d_ws;
  float* aggx  = ws;  ws += (size_t)TT * NN * 256;   // 164 MB
  float* den1  = ws;  ws += (size_t)TT * NN * 8;
  float* al1s  = ws;  ws += (size_t)TT * NN * 8;
  float* al1d  = ws;  ws += (size_t)TT * NN * 8;
  float* h2    = ws;  ws += (size_t)TT * NN * CD;
  float* al2s  = ws;  ws += (size_t)TT * NN;
  float* al2d  = ws;  ws += (size_t)TT * NN;
  float* agg2o = ws;  ws += (size_t)TT * NN * CD;
  float* sums  = ws;  ws += TT * CD;
  float* wsrc  = ws;  ws += 256;
  float* wdst  = ws;  ws += 256;
  float* W1T   = ws;  ws += D1 * 32;
  float* W2T   = ws;  ws += 32 * D1;
  int* rowptr = (int*)ws;
  int* fill   = rowptr + NN + 1;
  int* csr    = fill + NN;
  int* deg    = csr + NE;

  hipMemsetAsync(sums, 0, TT * CD * sizeof(float), stream);
  hipMemsetAsync(deg, 0, NN * sizeof(int), stream);

  k_deg<<<(NE + 255) / 256, 256, 0, stream>>>(dstp, deg);
  k_scan<<<1, 1024, 0, stream>>>(deg, rowptr, fill);
  k_fill<<<(NE + 255) / 256, 256, 0, stream>>>(srcp, dstp, fill, csr);
  k_prew<<<1, 256, 0, stream>>>(W1, as1, ad1, W2, wsrc, wdst, W1T, W2T);

  k_logits8<<<(NN / 32) * TT, 256, 0, stream>>>(x, wsrc, wdst, al1s, al1d);
  k_gat1<<<NN / 4, 256, 0, stream>>>(x, al1s, al1d, rowptr, csr, aggx, den1);
  k_post<<<(NN / 16) * TT, 256, 0, stream>>>(aggx, den1, W1T, b1, W2T, as2, ad2,
                                             h2, al2s, al2d);
  k_agg2<<<NN / 4, 256, 0, stream>>>(h2, al2s, al2d, rowptr, csr, b2, agg2o);
  k_lstm_all<<<NN / 16, 256, 0, stream>>>(agg2o, wih, whh, bih, bhh, out);

  k_sm_sum<<<dim3(25, TT), 256, 0, stream>>>(out, sums);
  k_sm_scale<<<dim3(25, TT), 256, 0, stream>>>(out, sums);
}